// Round 1
// baseline (174.143 us; speedup 1.0000x reference)
//
#include <hip/hip_runtime.h>

#define B_ 4
#define C_ 64
#define CI_ 32
#define N_ 4096
#define LOG2E 1.4426950408889634f

typedef __attribute__((ext_vector_type(8))) short bf16x8;
typedef __attribute__((ext_vector_type(4))) float f32x4;

__device__ __forceinline__ unsigned short f2bf_rne(float f) {
  unsigned u = __builtin_bit_cast(unsigned, f);
  unsigned r = (u + 0x7FFFu + ((u >> 16) & 1u)) >> 16;
  return (unsigned short)r;
}
__device__ __forceinline__ unsigned short f2bf_fast(float f) {
  unsigned u = __builtin_bit_cast(unsigned, f);
  return (unsigned short)((u + 0x8000u) >> 16);
}

// ---------------------------------------------------------------------------
// K1: 1x1-conv projections.
//   theta  [b][n][32] bf16, pre-scaled by log2(e)  (so exp(f) == exp2(f'))
//   phi    [b][m][32] bf16
//   gt     [b][i][m]  fp32  (transposed so K2's scaled write is coalesced)
// 3 waves/block, one output kind per wave, one position per lane.
// ---------------------------------------------------------------------------
__global__ __launch_bounds__(192) void k1_proj(
    const float* __restrict__ supp, const float* __restrict__ ref,
    const float* __restrict__ tw, const float* __restrict__ tb,
    const float* __restrict__ pw, const float* __restrict__ pb,
    const float* __restrict__ gw, const float* __restrict__ gb,
    unsigned short* __restrict__ theta, unsigned short* __restrict__ phi,
    float* __restrict__ gt)
{
  const int wave = threadIdx.x >> 6;
  const int lane = threadIdx.x & 63;
  const int p = blockIdx.x * 64 + lane;   // global position in [0, B*N)
  const int b = p >> 12;
  const int n = p & (N_ - 1);

  const float* W;  const float* bias;  const float* src;
  if (wave == 0)      { W = tw; bias = tb; src = supp; }
  else if (wave == 1) { W = pw; bias = pb; src = ref; }
  else                { W = gw; bias = gb; src = ref; }

  const float* x = src + (size_t)b * (C_ * N_) + n;   // stride-N column
  float acc[CI_];
#pragma unroll
  for (int i = 0; i < CI_; i++) acc[i] = bias[i];
  for (int c = 0; c < C_; c++) {
    float v = x[(size_t)c * N_];
#pragma unroll
    for (int i = 0; i < CI_; i++) acc[i] = fmaf(W[i * C_ + c], v, acc[i]);
  }

  if (wave == 0) {
    unsigned short* dst = theta + ((size_t)p << 5);
#pragma unroll
    for (int i = 0; i < CI_; i += 2) {
      unsigned lo = f2bf_rne(acc[i] * LOG2E);
      unsigned hi = f2bf_rne(acc[i + 1] * LOG2E);
      *(unsigned*)(dst + i) = lo | (hi << 16);
    }
  } else if (wave == 1) {
    unsigned short* dst = phi + ((size_t)p << 5);
#pragma unroll
    for (int i = 0; i < CI_; i += 2) {
      unsigned lo = f2bf_rne(acc[i]);
      unsigned hi = f2bf_rne(acc[i + 1]);
      *(unsigned*)(dst + i) = lo | (hi << 16);
    }
  } else {
    float* dst = gt + (size_t)b * (CI_ * N_) + n;
#pragma unroll
    for (int i = 0; i < CI_; i++) dst[(size_t)i * N_] = acc[i];  // coalesced across lanes
  }
}

// ---------------------------------------------------------------------------
// K2: column denominators den[m] = sum_n exp2(f'[n,m]), then
//     gy2t[b][i][m] = bf16( gt[b][i][m] / den[m] ).
// Block = (b, 64-m tile), 16 waves: wave = (n-quarter nq, m-subtile mw).
// Each wave: one 16x16x32 MFMA per 16 n-rows, K=Ci=32 in one shot.
// No max-subtraction needed (|f| bounded ~5 by construction).
// ---------------------------------------------------------------------------
__global__ __launch_bounds__(1024) void k2_den(
    const unsigned short* __restrict__ theta, const unsigned short* __restrict__ phi,
    const float* __restrict__ gt, unsigned short* __restrict__ gy2t)
{
  const int tid = threadIdx.x;
  const int wave = tid >> 6;
  const int lane = tid & 63;
  const int b = blockIdx.x >> 6;
  const int m0 = (blockIdx.x & 63) << 6;
  const int mw = wave & 3;          // m-subtile (16 cols)
  const int nq = wave >> 2;         // n-quarter (1024 rows)
  const int row16 = lane & 15;
  const int quad = lane >> 4;

  // B-operand: phi[m][i], lane -> B[col=m'=lane&15][k=i=quad*8+j], contiguous 16B
  bf16x8 bfrag = *(const bf16x8*)(phi +
      (((size_t)b * N_ + m0 + mw * 16 + row16) << 5) + (quad << 3));

  const unsigned short* abase = theta +
      (((size_t)b * N_ + nq * 1024 + row16) << 5) + (quad << 3);

  float d0 = 0.f, d1 = 0.f, d2 = 0.f, d3 = 0.f;
  f32x4 zero = {0.f, 0.f, 0.f, 0.f};
#pragma unroll 4
  for (int it = 0; it < 64; it++) {
    bf16x8 afrag = *(const bf16x8*)(abase + (it << 9));  // next 16 n-rows
    f32x4 f = __builtin_amdgcn_mfma_f32_16x16x32_bf16(afrag, bfrag, zero, 0, 0, 0);
    d0 += __builtin_amdgcn_exp2f(f[0]);
    d1 += __builtin_amdgcn_exp2f(f[1]);
    d2 += __builtin_amdgcn_exp2f(f[2]);
    d3 += __builtin_amdgcn_exp2f(f[3]);
  }
  // C-layout: this lane's 4 values all sit in column m0+mw*16+(lane&15).
  float den = (d0 + d1) + (d2 + d3);
  den += __shfl_xor(den, 16);
  den += __shfl_xor(den, 32);

  __shared__ float denp[4][64];
  if (lane < 16) denp[nq][mw * 16 + lane] = den;
  __syncthreads();

  for (int e = tid; e < CI_ * 64; e += 1024) {
    int i = e >> 6;
    int ml = e & 63;
    float dsum = denp[0][ml] + denp[1][ml] + denp[2][ml] + denp[3][ml];
    size_t idx = ((size_t)b * CI_ + i) * N_ + m0 + ml;
    gy2t[idx] = f2bf_rne(gt[idx] / dsum);
  }
}

// ---------------------------------------------------------------------------
// K3: x1[i,n] = sum_m exp2(f'[n,m]) * gy2t[i,m]; z = supp + w_w.x1 + w_b.
// Block = (b, 64-n tile), 16 waves: wave = (n-subtile ns, m-quarter q).
// Per iter (32 m): 2 f-MFMAs -> exp2 -> P to per-wave LDS (C->A layout
// round-trip, double-buffered) -> 2 PV-MFMAs. Partials combined with LDS
// fp32 atomics, then fused 64-channel output projection + residual.
// ---------------------------------------------------------------------------
__global__ __launch_bounds__(1024) void k3_attn(
    const unsigned short* __restrict__ theta, const unsigned short* __restrict__ phi,
    const unsigned short* __restrict__ gy2t, const float* __restrict__ supp,
    const float* __restrict__ ww, const float* __restrict__ wb,
    float* __restrict__ out)
{
  const int tid = threadIdx.x;
  const int wave = tid >> 6;
  const int lane = tid & 63;
  const int b = blockIdx.x >> 6;
  const int n0 = (blockIdx.x & 63) << 6;
  const int ns = wave & 3;          // n-subtile (16 rows)
  const int q = wave >> 2;          // m-quarter (1024 cols)
  const int row16 = lane & 15;
  const int quad = lane >> 4;

  // LDS: P stride 40 ushorts (80B) keeps b128 reads 16B-aligned, 2-way banks.
  __shared__ __align__(16) unsigned short Pbuf[16][2][640];  // 40 KB
  __shared__ float wwlds[C_ * 33];                           // 8.25 KB
  __shared__ float x1sum[4][CI_ * 17 + 1];                   // 8.5 KB (pad breaks bank alias)

  for (int e = tid; e < 4 * (CI_ * 17 + 1); e += 1024) ((float*)x1sum)[e] = 0.f;
  for (int e = tid; e < C_ * CI_; e += 1024) wwlds[(e >> 5) * 33 + (e & 31)] = ww[e];
  __syncthreads();

  const int nbase = n0 + ns * 16;
  bf16x8 afrag = *(const bf16x8*)(theta +
      (((size_t)b * N_ + nbase + row16) << 5) + (quad << 3));

  f32x4 x1a = {0.f,0.f,0.f,0.f}, x1b = {0.f,0.f,0.f,0.f};
  f32x4 zero = {0.f,0.f,0.f,0.f};

  for (int it = 0; it < 32; it++) {
    const int m0 = q * 1024 + it * 32;
    const unsigned short* pb = phi + (((size_t)b * N_ + m0 + row16) << 5) + (quad << 3);
    bf16x8 b0 = *(const bf16x8*)pb;
    bf16x8 b1 = *(const bf16x8*)(pb + 512);   // +16 m-rows
    f32x4 f0 = __builtin_amdgcn_mfma_f32_16x16x32_bf16(afrag, b0, zero, 0, 0, 0);
    f32x4 f1 = __builtin_amdgcn_mfma_f32_16x16x32_bf16(afrag, b1, zero, 0, 0, 0);

    unsigned short* P = &Pbuf[wave][it & 1][0];
    unsigned short* wr = P + quad * 4 * 40 + row16;   // C-layout: row=quad*4+r, col=row16
#pragma unroll
    for (int r = 0; r < 4; r++) {
      wr[r * 40]      = f2bf_fast(__builtin_amdgcn_exp2f(f0[r]));
      wr[r * 40 + 16] = f2bf_fast(__builtin_amdgcn_exp2f(f1[r]));
    }
    // A-layout read back: row=lane&15, k=quad*8..+7 (one 16B ds_read)
    bf16x8 pa = *(const bf16x8*)(P + row16 * 40 + quad * 8);

    // B-operand gy2t[i][m]: lane -> B[col=i=lane&15(+16)][k=m-local], 16B contiguous
    const unsigned short* g0 = gy2t + ((size_t)b * CI_ + row16) * N_ + m0 + (quad << 3);
    bf16x8 gb0 = *(const bf16x8*)g0;
    bf16x8 gb1 = *(const bf16x8*)(g0 + 16 * N_);
    x1a = __builtin_amdgcn_mfma_f32_16x16x32_bf16(pa, gb0, x1a, 0, 0, 0);
    x1b = __builtin_amdgcn_mfma_f32_16x16x32_bf16(pa, gb1, x1b, 0, 0, 0);
  }

  // combine m-quarter partials: x1sum[ns][i*17 + n_local]
  float* xs = &x1sum[ns][0];
#pragma unroll
  for (int r = 0; r < 4; r++) {
    atomicAdd(&xs[row16 * 17 + quad * 4 + r], x1a[r]);
    atomicAdd(&xs[(row16 + 16) * 17 + quad * 4 + r], x1b[r]);
  }
  __syncthreads();

  // fused output projection + residual: thread -> (c, 4 consecutive n)
  const int c = tid >> 4;
  const int ng = tid & 15;
  const int reg = ng >> 2;          // which 16-n region
  const int nl = (ng & 3) * 4;      // n offset within region
  float a0 = wb[c], a1 = a0, a2 = a0, a3 = a0;
  const float* xr0 = &x1sum[reg][nl];
#pragma unroll 8
  for (int i = 0; i < CI_; i++) {
    float wv = wwlds[c * 33 + i];
    const float* xr = xr0 + i * 17;
    a0 = fmaf(wv, xr[0], a0);
    a1 = fmaf(wv, xr[1], a1);
    a2 = fmaf(wv, xr[2], a2);
    a3 = fmaf(wv, xr[3], a3);
  }
  size_t ob = ((size_t)b * C_ + c) * N_ + n0 + ng * 4;
  float4 s = *(const float4*)(supp + ob);
  float4 o;
  o.x = a0 + s.x; o.y = a1 + s.y; o.z = a2 + s.z; o.w = a3 + s.w;
  *(float4*)(out + ob) = o;
}

extern "C" void kernel_launch(void* const* d_in, const int* in_sizes, int n_in,
                              void* d_out, int out_size, void* d_ws, size_t ws_size,
                              hipStream_t stream)
{
  const float* supp = (const float*)d_in[0];
  const float* ref  = (const float*)d_in[1];
  const float* tw   = (const float*)d_in[2];
  const float* tb   = (const float*)d_in[3];
  const float* pw   = (const float*)d_in[4];
  const float* pb   = (const float*)d_in[5];
  const float* gw   = (const float*)d_in[6];
  const float* gb   = (const float*)d_in[7];
  const float* ww   = (const float*)d_in[8];
  const float* wb   = (const float*)d_in[9];
  float* out = (float*)d_out;

  char* ws = (char*)d_ws;
  unsigned short* theta = (unsigned short*)ws;                   // 1 MB
  unsigned short* phi   = (unsigned short*)(ws + (1u << 20));    // 1 MB
  float*          gt    = (float*)(ws + (2u << 20));             // 2 MB
  unsigned short* gy2t  = (unsigned short*)(ws + (4u << 20));    // 1 MB
  // total 5 MB of d_ws; every byte we read is written first each launch.

  hipLaunchKernelGGL(k1_proj, dim3(256), dim3(192), 0, stream,
                     supp, ref, tw, tb, pw, pb, gw, gb, theta, phi, gt);
  hipLaunchKernelGGL(k2_den, dim3(256), dim3(1024), 0, stream,
                     theta, phi, gt, gy2t);
  hipLaunchKernelGGL(k3_attn, dim3(256), dim3(1024), 0, stream,
                     theta, phi, gy2t, supp, ww, wb, out);
}

// Round 2
// 149.065 us; speedup vs baseline: 1.1682x; 1.1682x over previous
//
#include <hip/hip_runtime.h>

#define C_ 64
#define CI_ 32
#define N_ 4096
#define LOG2E 1.4426950408889634f

typedef __attribute__((ext_vector_type(8))) short bf16x8;
typedef __attribute__((ext_vector_type(4))) float f32x4;

__device__ __forceinline__ unsigned short f2bf_rne(float f) {
  unsigned u = __builtin_bit_cast(unsigned, f);
  unsigned r = (u + 0x7FFFu + ((u >> 16) & 1u)) >> 16;
  return (unsigned short)r;
}
__device__ __forceinline__ unsigned pack_bf2(float lo, float hi) {
  unsigned a = (__builtin_bit_cast(unsigned, lo) + 0x8000u) >> 16;
  unsigned b = (__builtin_bit_cast(unsigned, hi) + 0x8000u) & 0xFFFF0000u;
  return a | b;
}

// ---------------------------------------------------------------------------
// K1: projections. theta[p][32] bf16 (x log2e), phi[p][32] bf16, gt[b][i][m] f32.
// 768 blocks x 256 thr: block = (proj, 64-position tile); wave = channel-octet.
// ---------------------------------------------------------------------------
__global__ __launch_bounds__(256) void k1_proj(
    const float* __restrict__ supp, const float* __restrict__ ref,
    const float* __restrict__ tw, const float* __restrict__ tb,
    const float* __restrict__ pw, const float* __restrict__ pb,
    const float* __restrict__ gw, const float* __restrict__ gb,
    unsigned short* __restrict__ theta, unsigned short* __restrict__ phi,
    float* __restrict__ gt)
{
  const int proj = blockIdx.x >> 8;
  const int pblk = blockIdx.x & 255;
  const int o = __builtin_amdgcn_readfirstlane(threadIdx.x >> 6);
  const int lane = threadIdx.x & 63;
  const int p = pblk * 64 + lane;
  const int b = p >> 12;
  const int n = p & (N_ - 1);

  const float *W, *bias, *src;
  if (proj == 0)      { W = tw; bias = tb; src = supp; }
  else if (proj == 1) { W = pw; bias = pb; src = ref; }
  else                { W = gw; bias = gb; src = ref; }

  const float* x = src + (size_t)b * (C_ * N_) + n;
  const float* Wo = W + o * 8 * C_;
  float acc[8];
#pragma unroll
  for (int k = 0; k < 8; k++) acc[k] = bias[o * 8 + k];
#pragma unroll 8
  for (int c = 0; c < C_; c++) {
    float v = x[(size_t)c * N_];
#pragma unroll
    for (int k = 0; k < 8; k++) acc[k] = fmaf(Wo[k * C_ + c], v, acc[k]);
  }

  if (proj == 0) {
    unsigned pk[4];
#pragma unroll
    for (int k = 0; k < 4; k++)
      pk[k] = (unsigned)f2bf_rne(acc[2 * k] * LOG2E) |
              ((unsigned)f2bf_rne(acc[2 * k + 1] * LOG2E) << 16);
    *(uint4*)(theta + ((size_t)p << 5) + o * 8) = *(uint4*)pk;
  } else if (proj == 1) {
    unsigned pk[4];
#pragma unroll
    for (int k = 0; k < 4; k++)
      pk[k] = (unsigned)f2bf_rne(acc[2 * k]) |
              ((unsigned)f2bf_rne(acc[2 * k + 1]) << 16);
    *(uint4*)(phi + ((size_t)p << 5) + o * 8) = *(uint4*)pk;
  } else {
    float* dst = gt + ((size_t)b * CI_ + o * 8) * N_ + n;
#pragma unroll
    for (int k = 0; k < 8; k++) dst[(size_t)k * N_] = acc[k];
  }
}

// ---------------------------------------------------------------------------
// K2: den[m] = sum_n exp2(f'[n,m]); gy2i[b][i][sigma(m)] = bf16(gt/den).
// Block = (b, 64-m tile); 16 waves = (nq 0..7 x mw 0..1); wave: 2 B-frags,
// 32 iters over its 512-n slice, depth-2 A prefetch.
// sigma interleaves m within each 32-chunk: pos = 2*(m&15) + (m>>4&1).
// ---------------------------------------------------------------------------
__global__ __launch_bounds__(1024) void k2_den(
    const unsigned short* __restrict__ theta, const unsigned short* __restrict__ phi,
    const float* __restrict__ gt, unsigned short* __restrict__ gy2i)
{
  const int tid = threadIdx.x;
  const int wave = tid >> 6;
  const int lane = tid & 63;
  const int b = blockIdx.x >> 6;
  const int m0 = (blockIdx.x & 63) << 6;
  const int mw = wave & 1;
  const int nq = wave >> 1;
  const int row16 = lane & 15;
  const int quad = lane >> 4;

  const unsigned short* pbase = phi +
      (((size_t)b * N_ + m0 + mw * 32 + row16) << 5) + (quad << 3);
  bf16x8 bf0 = *(const bf16x8*)pbase;
  bf16x8 bf1 = *(const bf16x8*)(pbase + 512);

  const unsigned short* abase = theta +
      (((size_t)b * N_ + nq * 512 + row16) << 5) + (quad << 3);

  f32x4 zero = {0.f, 0.f, 0.f, 0.f};
  float d[8];
#pragma unroll
  for (int k = 0; k < 8; k++) d[k] = 0.f;

  bf16x8 a0 = *(const bf16x8*)(abase);
  bf16x8 a1 = *(const bf16x8*)(abase + 512);
#pragma unroll 2
  for (int it = 0; it < 32; it++) {
    int itn = it + 2 <= 31 ? it + 2 : 31;
    bf16x8 an = *(const bf16x8*)(abase + ((size_t)itn << 9));
    f32x4 f0 = __builtin_amdgcn_mfma_f32_16x16x32_bf16(a0, bf0, zero, 0, 0, 0);
    f32x4 f1 = __builtin_amdgcn_mfma_f32_16x16x32_bf16(a0, bf1, zero, 0, 0, 0);
#pragma unroll
    for (int r = 0; r < 4; r++) {
      d[r]     += __builtin_amdgcn_exp2f(f0[r]);
      d[4 + r] += __builtin_amdgcn_exp2f(f1[r]);
    }
    a0 = a1; a1 = an;
  }
  float dena = (d[0] + d[1]) + (d[2] + d[3]);
  float denb = (d[4] + d[5]) + (d[6] + d[7]);
  dena += __shfl_xor(dena, 16); dena += __shfl_xor(dena, 32);
  denb += __shfl_xor(denb, 16); denb += __shfl_xor(denb, 32);

  __shared__ float denp[8][64];
  if (lane < 16) {
    denp[nq][mw * 32 + lane] = dena;
    denp[nq][mw * 32 + 16 + lane] = denb;
  }
  __syncthreads();

  for (int e = tid; e < CI_ * 64; e += 1024) {
    int i = e >> 6;
    int ml = e & 63;
    float ds = ((denp[0][ml] + denp[1][ml]) + (denp[2][ml] + denp[3][ml])) +
               ((denp[4][ml] + denp[5][ml]) + (denp[6][ml] + denp[7][ml]));
    int within = ml & 31;
    int pos = ((within & 15) << 1) | (within >> 4);
    size_t rowb = ((size_t)b * CI_ + i) * N_ + m0;
    gy2i[rowb + (ml & 32) + pos] = f2bf_rne(gt[rowb + ml] / ds);
  }
}

// ---------------------------------------------------------------------------
// K3: x1[i,n] = sum_m exp2(f') * gy2[i,m]; z = supp + ww.x1 + wb.
// Block = (b, 64-n tile); 16 waves = (ns 0..3 x q 0..3). Software-pipelined:
// read P(it-1) / f-MFMA(it) / prefetch phi(it+1) / exp+pack+write P(it) /
// PV(it-1) / prefetch gy2(it). P stored k-interleaved (matches gy2i's sigma)
// so writes are 4x ds_write_b32; row stride 80B -> 2-way banks (free).
// ---------------------------------------------------------------------------
__global__ __launch_bounds__(1024) void k3_attn(
    const unsigned short* __restrict__ theta, const unsigned short* __restrict__ phi,
    const unsigned short* __restrict__ gy2i, const float* __restrict__ supp,
    const float* __restrict__ ww, const float* __restrict__ wb,
    float* __restrict__ out)
{
  const int tid = threadIdx.x;
  const int wave = tid >> 6;
  const int lane = tid & 63;
  const int b = blockIdx.x >> 6;
  const int n0 = (blockIdx.x & 63) << 6;
  const int ns = wave & 3;
  const int q = wave >> 2;
  const int row16 = lane & 15;
  const int quad = lane >> 4;

  __shared__ __align__(16) unsigned short Pbuf[16][2][640];  // 40 KB
  __shared__ float wwlds[C_ * 33];                           // 8.25 KB
  __shared__ float x1sum[4][CI_ * 17 + 1];                   // 8.7 KB

  for (int e = tid; e < 4 * (CI_ * 17 + 1); e += 1024) ((float*)x1sum)[e] = 0.f;
  for (int e = tid; e < C_ * CI_; e += 1024) wwlds[(e >> 5) * 33 + (e & 31)] = ww[e];
  __syncthreads();

  bf16x8 afrag = *(const bf16x8*)(theta +
      (((size_t)b * N_ + n0 + ns * 16 + row16) << 5) + (quad << 3));

  const unsigned short* pb = phi +
      (((size_t)b * N_ + q * 1024 + row16) << 5) + (quad << 3);
  const unsigned short* gp = gy2i +
      ((size_t)b * CI_ + row16) * N_ + q * 1024 + (quad << 3);

  const int wr_off = quad * 4 * 40 + 2 * row16;   // dword-aligned ushort offset
  const int rd_off = row16 * 40 + quad * 8;

  f32x4 zero = {0.f, 0.f, 0.f, 0.f};
  f32x4 x1a = zero, x1b = zero;

  // prologue: iter 0
  bf16x8 cb0 = *(const bf16x8*)pb;
  bf16x8 cb1 = *(const bf16x8*)(pb + 512);
  f32x4 f0 = __builtin_amdgcn_mfma_f32_16x16x32_bf16(afrag, cb0, zero, 0, 0, 0);
  f32x4 f1 = __builtin_amdgcn_mfma_f32_16x16x32_bf16(afrag, cb1, zero, 0, 0, 0);
  bf16x8 nb0 = *(const bf16x8*)(pb + 1024);
  bf16x8 nb1 = *(const bf16x8*)(pb + 1536);
  bf16x8 cg0 = *(const bf16x8*)gp;
  bf16x8 cg1 = *(const bf16x8*)(gp + (size_t)16 * N_);
  {
    unsigned short* base = &Pbuf[wave][0][wr_off];
#pragma unroll
    for (int r = 0; r < 4; r++)
      *(unsigned*)(base + r * 40) =
          pack_bf2(__builtin_amdgcn_exp2f(f0[r]), __builtin_amdgcn_exp2f(f1[r]));
  }

  for (int it = 1; it < 32; it++) {
    bf16x8 pa = *(const bf16x8*)&Pbuf[wave][(it - 1) & 1][rd_off];
    f0 = __builtin_amdgcn_mfma_f32_16x16x32_bf16(afrag, nb0, zero, 0, 0, 0);
    f1 = __builtin_amdgcn_mfma_f32_16x16x32_bf16(afrag, nb1, zero, 0, 0, 0);
    int itn = it + 1 <= 31 ? it + 1 : 31;
    nb0 = *(const bf16x8*)(pb + itn * 1024);
    nb1 = *(const bf16x8*)(pb + itn * 1024 + 512);
    {
      unsigned short* base = &Pbuf[wave][it & 1][wr_off];
#pragma unroll
      for (int r = 0; r < 4; r++)
        *(unsigned*)(base + r * 40) =
            pack_bf2(__builtin_amdgcn_exp2f(f0[r]), __builtin_amdgcn_exp2f(f1[r]));
    }
    x1a = __builtin_amdgcn_mfma_f32_16x16x32_bf16(pa, cg0, x1a, 0, 0, 0);
    x1b = __builtin_amdgcn_mfma_f32_16x16x32_bf16(pa, cg1, x1b, 0, 0, 0);
    cg0 = *(const bf16x8*)(gp + it * 32);
    cg1 = *(const bf16x8*)(gp + (size_t)16 * N_ + it * 32);
  }
  // epilogue: PV(31)
  {
    bf16x8 pa = *(const bf16x8*)&Pbuf[wave][31 & 1][rd_off];
    x1a = __builtin_amdgcn_mfma_f32_16x16x32_bf16(pa, cg0, x1a, 0, 0, 0);
    x1b = __builtin_amdgcn_mfma_f32_16x16x32_bf16(pa, cg1, x1b, 0, 0, 0);
  }

  float* xs = &x1sum[ns][0];
#pragma unroll
  for (int r = 0; r < 4; r++) {
    atomicAdd(&xs[row16 * 17 + quad * 4 + r], x1a[r]);
    atomicAdd(&xs[(row16 + 16) * 17 + quad * 4 + r], x1b[r]);
  }
  __syncthreads();

  const int c = tid >> 4;
  const int ng = tid & 15;
  const int reg = ng >> 2;
  const int nl = (ng & 3) * 4;
  float a0 = wb[c], a1 = a0, a2 = a0, a3 = a0;
  const float* xr0 = &x1sum[reg][nl];
#pragma unroll 8
  for (int i = 0; i < CI_; i++) {
    float wv = wwlds[c * 33 + i];
    const float* xr = xr0 + i * 17;
    a0 = fmaf(wv, xr[0], a0);
    a1 = fmaf(wv, xr[1], a1);
    a2 = fmaf(wv, xr[2], a2);
    a3 = fmaf(wv, xr[3], a3);
  }
  size_t ob = ((size_t)b * C_ + c) * N_ + n0 + ng * 4;
  float4 s = *(const float4*)(supp + ob);
  float4 o;
  o.x = a0 + s.x; o.y = a1 + s.y; o.z = a2 + s.z; o.w = a3 + s.w;
  *(float4*)(out + ob) = o;
}

extern "C" void kernel_launch(void* const* d_in, const int* in_sizes, int n_in,
                              void* d_out, int out_size, void* d_ws, size_t ws_size,
                              hipStream_t stream)
{
  const float* supp = (const float*)d_in[0];
  const float* ref  = (const float*)d_in[1];
  const float* tw   = (const float*)d_in[2];
  const float* tb   = (const float*)d_in[3];
  const float* pw   = (const float*)d_in[4];
  const float* pb   = (const float*)d_in[5];
  const float* gw   = (const float*)d_in[6];
  const float* gb   = (const float*)d_in[7];
  const float* ww   = (const float*)d_in[8];
  const float* wb   = (const float*)d_in[9];
  float* out = (float*)d_out;

  char* ws = (char*)d_ws;
  unsigned short* theta = (unsigned short*)ws;                   // 1 MB
  unsigned short* phi   = (unsigned short*)(ws + (1u << 20));    // 1 MB
  float*          gt    = (float*)(ws + (2u << 20));             // 2 MB
  unsigned short* gy2i  = (unsigned short*)(ws + (4u << 20));    // 1 MB

  hipLaunchKernelGGL(k1_proj, dim3(768), dim3(256), 0, stream,
                     supp, ref, tw, tb, pw, pb, gw, gb, theta, phi, gt);
  hipLaunchKernelGGL(k2_den, dim3(256), dim3(1024), 0, stream,
                     theta, phi, gt, gy2i);
  hipLaunchKernelGGL(k3_attn, dim3(256), dim3(1024), 0, stream,
                     theta, phi, gy2i, supp, ww, wb, out);
}